// Round 5
// baseline (292.225 us; speedup 1.0000x reference)
//
#include <hip/hip_runtime.h>

#define DEVI __device__ __forceinline__

typedef unsigned short u16;
typedef unsigned int   u32;
typedef u16  u16x8 __attribute__((ext_vector_type(8)));
typedef u16  u16x4 __attribute__((ext_vector_type(4)));
typedef short bf16x8 __attribute__((ext_vector_type(8)));
typedef float f32x4 __attribute__((ext_vector_type(4)));

static constexpr int BB = 16, NN = 4096, GG = 1024;
static constexpr int D1 = 128, D2 = 256, CIN = 384, CH = 256;

DEVI float bf2f(u16 h) { u32 u = ((u32)h) << 16; float f; __builtin_memcpy(&f, &u, 4); return f; }
DEVI u16 f2bf(float f) {
    u32 u; __builtin_memcpy(&u, &f, 4);
    u32 r = (u + 0x7fffu + ((u >> 16) & 1u)) >> 16;
    return (u16)r;
}

DEVI void gload16(const void* g, void* l) {
    __builtin_amdgcn_global_load_lds((const __attribute__((address_space(1))) void*)g,
                                     (__attribute__((address_space(3))) void*)l, 16, 0, 0);
}

// ---------------- weight conversion fp32 -> bf16 ----------------
__global__ void k_convw(const float* __restrict__ W1, const float* __restrict__ W2,
                        u16* __restrict__ W1b, u16* __restrict__ W2b) {
    int i = blockIdx.x * 256 + threadIdx.x;
    if (i < CH * CIN) W1b[i] = f2bf(W1[i]);
    int j = i - CH * CIN;
    if (j >= 0 && j < CH * CH) W2b[j] = f2bf(W2[j]);
}

// ---------------- feature2 transpose: [B][256][1024] f32 -> [B][1024][256] bf16 ----------------
__global__ void k_f2t(const float* __restrict__ f2, u16* __restrict__ f2t) {
    int b = blockIdx.z, ct = blockIdx.y, gt = blockIdx.x;
    __shared__ u16 tile[64][65];
    int t = threadIdx.x; int g = t & 63; int q = t >> 6;
    for (int p = 0; p < 16; ++p) {
        int cl = p * 4 + q;
        tile[g][cl] = f2bf(f2[((size_t)(b * D2 + ct * 64 + cl)) * GG + gt * 64 + g]);
    }
    __syncthreads();
    for (int p = 0; p < 16; ++p) {
        int gl = p * 4 + q;
        f2t[((size_t)(b * GG + gt * 64 + gl)) * D2 + ct * 64 + g] = tile[gl][g];
    }
}

// ---------------- 3-NN: 4 threads/query, branchless fp32 top-4 scan, fp64 re-rank of 16 ----------------
__global__ __launch_bounds__(256) void k_knn(const float* __restrict__ c1, const float* __restrict__ c2,
                                             int* __restrict__ idxo, float* __restrict__ wo) {
    int b = blockIdx.y; int t = threadIdx.x;
    int q = t >> 2, s = t & 3;
    int n = blockIdx.x * 64 + q;
    __shared__ float4 sp[GG];
    __shared__ int mi[256][4];
    const float* cb = c2 + (size_t)b * 3 * GG;
    for (int i = t; i < GG; i += 256) {
        float x = cb[i], y = cb[GG + i], z = cb[2 * GG + i];
        sp[i] = make_float4(x, y, z, x * x + y * y + z * z);
    }
    __syncthreads();
    const float* pb = c1 + (size_t)b * 3 * NN;
    float px = pb[n], py = pb[NN + n], pz = pb[2 * NN + n];
    float pn = px * px + py * py + pz * pz;
    float d0 = 3.4e38f, d1 = 3.4e38f, d2 = 3.4e38f, d3 = 3.4e38f;
    int i0 = 0, i1 = 0, i2 = 0, i3 = 0;
    for (int gb = 0; gb < GG; gb += 16) {
        #pragma unroll
        for (int u = 0; u < 4; ++u) {
            int g = gb + u * 4 + s;
            float4 p = sp[g];
            float dot = px * p.x + py * p.y + pz * p.z;
            float d = pn + p.w - 2.f * dot;
            // branchless sorted insertion (strict <, incumbent wins ties) — identical
            // selection semantics to the branchy version, no exec-mask divergence.
            bool c0 = d < d0, c1 = d < d1, c2 = d < d2, c3 = d < d3;
            d3 = c2 ? d2 : (c3 ? d : d3);  i3 = c2 ? i2 : (c3 ? g : i3);
            d2 = c1 ? d1 : (c2 ? d : d2);  i2 = c1 ? i1 : (c2 ? g : i2);
            d1 = c0 ? d0 : (c1 ? d : d1);  i1 = c0 ? i0 : (c1 ? g : i1);
            d0 = c0 ? d  : d0;             i0 = c0 ? g : i0;
        }
    }
    mi[t][0] = i0; mi[t][1] = i1; mi[t][2] = i2; mi[t][3] = i3;
    __syncthreads();
    if (s == 0) {
        // lexicographic (dist, idx) streaming top-3 over the 16 candidates, fp64
        double e0 = 1e300, e1 = 1e300, e2 = 1e300;
        int j0 = 0x7fffffff, j1 = 0x7fffffff, j2 = 0x7fffffff;
        #pragma unroll 4
        for (int k = 0; k < 16; ++k) {
            int g = mi[q * 4 + (k >> 2)][k & 3];
            float4 p = sp[g];
            double dx = (double)px - (double)p.x;
            double dy = (double)py - (double)p.y;
            double dz = (double)pz - (double)p.z;
            double d = dx * dx + dy * dy + dz * dz;
            bool lt2 = d < e2 || (d == e2 && g < j2);
            if (lt2) {
                bool lt1 = d < e1 || (d == e1 && g < j1);
                if (lt1) {
                    e2 = e1; j2 = j1;
                    bool lt0 = d < e0 || (d == e0 && g < j0);
                    if (lt0) { e1 = e0; j1 = j0; e0 = d; j0 = g; }
                    else { e1 = d; j1 = g; }
                } else { e2 = d; j2 = g; }
            }
        }
        float r0 = 1.f / ((float)e0 + 1e-8f);
        float r1 = 1.f / ((float)e1 + 1e-8f);
        float r2 = 1.f / ((float)e2 + 1e-8f);
        float sum = r0 + r1 + r2;
        size_t base = ((size_t)b * NN + n) * 3;
        idxo[base] = j0; idxo[base + 1] = j1; idxo[base + 2] = j2;
        wo[base] = r0 / sum; wo[base + 1] = r1 / sum; wo[base + 2] = r2 / sum;
    }
}

// ---------------- build X [B*N][384] bf16: cols 0..127 = feature1^T, 128..383 = interp ----------------
__global__ void k_pack(const float* __restrict__ f1, const u16* __restrict__ f2t,
                       const int* __restrict__ idxo, const float* __restrict__ wo,
                       u16* __restrict__ Xp) {
    int b = blockIdx.y; int n0 = blockIdx.x * 64;
    __shared__ u16 Xt[64][392];          // 384 + 8 pad (row stride 784 B = 49*16 -> aligned, conflict-light)
    int t = threadIdx.x; int j = t & 63; int q = t >> 6;
    // feature1 part
    for (int p = 0; p < 4; ++p) {
        int oct = p * 4 + q; int cb = oct * 8;
        u16x8 o;
        #pragma unroll
        for (int k = 0; k < 8; ++k)
            o[k] = f2bf(f1[((size_t)(b * D1 + cb + k)) * NN + n0 + j]);
        *(u16x8*)&Xt[j][cb] = o;
    }
    // interp part
    size_t bn = (size_t)b * NN + n0 + j;
    int g0 = idxo[bn * 3], g1 = idxo[bn * 3 + 1], g2 = idxo[bn * 3 + 2];
    float w0 = wo[bn * 3], w1 = wo[bn * 3 + 1], w2 = wo[bn * 3 + 2];
    const u16* r0 = f2t + ((size_t)b * GG + g0) * D2;
    const u16* r1 = f2t + ((size_t)b * GG + g1) * D2;
    const u16* r2 = f2t + ((size_t)b * GG + g2) * D2;
    for (int p = 0; p < 8; ++p) {
        int oct = p * 4 + q; int cb = oct * 8;
        u16x8 a = *(const u16x8*)(r0 + cb);
        u16x8 bb = *(const u16x8*)(r1 + cb);
        u16x8 cc = *(const u16x8*)(r2 + cb);
        u16x8 o;
        #pragma unroll
        for (int k = 0; k < 8; ++k)
            o[k] = f2bf(w0 * bf2f(a[k]) + w1 * bf2f(bb[k]) + w2 * bf2f(cc[k]));
        *(u16x8*)&Xt[j][D1 + cb] = o;
    }
    __syncthreads();
    // linear copy-out (global side is fully contiguous)
    u16* dst = Xp + ((size_t)b * NN + n0) * CIN;
    for (int p = 0; p < 12; ++p) {
        int ci = p * 256 + t;           // 0..3071 chunks of 8 u16
        int row = ci / 48, ch = ci % 48;
        *(u16x8*)(dst + (size_t)ci * 8) = *(const u16x8*)&Xt[row][ch * 8];
    }
}

// ---------------- GEMM: Y[n][c] (bf16) = A[256][K] * X[n][K]^T + bias, fused BN stats ----------------
// Double-buffered LDS: STAGE(next) issued before compute(cur); the single
// __syncthreads per step (implicit vmcnt(0)+lgkmcnt(0) drain) lands AFTER the
// MFMA work, so next-tile global_load_lds latency hides under compute.
template<int K>
__global__ __launch_bounds__(256) void k_gemm(const u16* __restrict__ A, const u16* __restrict__ Bm,
                                              const float* __restrict__ bias, u16* __restrict__ Yp,
                                              float* __restrict__ S1, float* __restrict__ S2) {
    constexpr int NK = K / 32;
    int nt = blockIdx.x, mt = blockIdx.y, b = blockIdx.z;
    int c0 = mt * 128; size_t n0 = (size_t)b * NN + nt * 128;
    __shared__ u16 Al[2][128 * 32], Bl[2][128 * 32];
    __shared__ float sred[4][64], qred[4][64];
    int t = threadIdx.x, lane = t & 63, w = t >> 6;
    int wr = w >> 1, wc = w & 1;
    f32x4 acc[4][4];
    #pragma unroll
    for (int m = 0; m < 4; ++m)
        #pragma unroll
        for (int n = 0; n < 4; ++n) acc[m][n] = (f32x4){0.f, 0.f, 0.f, 0.f};
    int lr = w * 32 + (lane >> 2);
    int lc = (lane & 3) * 8;

    // prologue: stage K-step 0 into buffer 0
    #pragma unroll
    for (int i = 0; i < 2; ++i) {
        gload16(A + (size_t)(c0 + lr + i * 16) * K + lc, &Al[0][(w * 32 + i * 16) * 32]);
        gload16(Bm + (n0 + lr + i * 16) * K + lc, &Bl[0][(w * 32 + i * 16) * 32]);
    }
    __syncthreads();

    for (int ks = 0; ks < NK; ++ks) {
        int cur = ks & 1;
        if (ks + 1 < NK) {
            #pragma unroll
            for (int i = 0; i < 2; ++i) {
                gload16(A + (size_t)(c0 + lr + i * 16) * K + (ks + 1) * 32 + lc, &Al[cur ^ 1][(w * 32 + i * 16) * 32]);
                gload16(Bm + (n0 + lr + i * 16) * K + (ks + 1) * 32 + lc, &Bl[cur ^ 1][(w * 32 + i * 16) * 32]);
            }
        }
        bf16x8 af[4], bfr[4];
        #pragma unroll
        for (int m = 0; m < 4; ++m)
            af[m] = *(const bf16x8*)&Al[cur][(wr * 64 + m * 16 + (lane & 15)) * 32 + (lane >> 4) * 8];
        #pragma unroll
        for (int n = 0; n < 4; ++n)
            bfr[n] = *(const bf16x8*)&Bl[cur][(wc * 64 + n * 16 + (lane & 15)) * 32 + (lane >> 4) * 8];
        #pragma unroll
        for (int m = 0; m < 4; ++m)
            #pragma unroll
            for (int n = 0; n < 4; ++n)
                acc[m][n] = __builtin_amdgcn_mfma_f32_16x16x32_bf16(af[m], bfr[n], acc[m][n], 0, 0, 0);
        __syncthreads();   // drains this wave's next-stage loads (vmcnt0) + syncs buffers
    }
    // epilogue: bias + bf16 store + per-channel partial sums (y and y^2) over this block's 128 cols
    float sacc[4][4], qacc[4][4];
    #pragma unroll
    for (int m = 0; m < 4; ++m) {
        int c = c0 + wr * 64 + m * 16 + (lane >> 4) * 4;
        float b0 = bias[c], b1 = bias[c + 1], b2 = bias[c + 2], b3 = bias[c + 3];
        #pragma unroll
        for (int j = 0; j < 4; ++j) { sacc[m][j] = 0.f; qacc[m][j] = 0.f; }
        #pragma unroll
        for (int n = 0; n < 4; ++n) {
            size_t nn = n0 + wc * 64 + n * 16 + (lane & 15);
            f32x4 v = acc[m][n];
            float y0 = v[0] + b0, y1 = v[1] + b1, y2 = v[2] + b2, y3 = v[3] + b3;
            u16x4 o;
            o[0] = f2bf(y0); o[1] = f2bf(y1); o[2] = f2bf(y2); o[3] = f2bf(y3);
            *(u16x4*)(Yp + nn * CH + c) = o;
            sacc[m][0] += y0; qacc[m][0] += y0 * y0;
            sacc[m][1] += y1; qacc[m][1] += y1 * y1;
            sacc[m][2] += y2; qacc[m][2] += y2 * y2;
            sacc[m][3] += y3; qacc[m][3] += y3 * y3;
        }
    }
    // reduce across the 16 lane-columns (bits 0..3 of lane; bits 4..5 = channel group)
    #pragma unroll
    for (int m = 0; m < 4; ++m)
        #pragma unroll
        for (int j = 0; j < 4; ++j) {
            float s = sacc[m][j], qv = qacc[m][j];
            #pragma unroll
            for (int mask = 1; mask <= 8; mask <<= 1) {
                s  += __shfl_xor(s, mask);
                qv += __shfl_xor(qv, mask);
            }
            sacc[m][j] = s; qacc[m][j] = qv;
        }
    int g = lane >> 4;
    if ((lane & 15) == 0) {
        #pragma unroll
        for (int m = 0; m < 4; ++m)
            #pragma unroll
            for (int j = 0; j < 4; ++j) {
                sred[w][m * 16 + g * 4 + j] = sacc[m][j];
                qred[w][m * 16 + g * 4 + j] = qacc[m][j];
            }
    }
    __syncthreads();
    if (t < 128) {
        int half = t >> 6, cl = t & 63;
        float s  = sred[half * 2][cl] + sred[half * 2 + 1][cl];
        float qv = qred[half * 2][cl] + qred[half * 2 + 1][cl];
        atomicAdd(&S1[c0 + half * 64 + cl], s);
        atomicAdd(&S2[c0 + half * 64 + cl], qv);
    }
}

// ---------------- finalize BN scale/shift ----------------
__global__ void k_fin(const float* __restrict__ S1, const float* __restrict__ S2,
                      const float* __restrict__ gamma, const float* __restrict__ beta,
                      float* __restrict__ scale, float* __restrict__ shift) {
    int c = threadIdx.x;
    float inv = 1.f / 65536.f;
    float m = S1[c] * inv;
    float v = S2[c] * inv - m * m;
    float sc = gamma[c] * rsqrtf(v + 1e-5f);
    scale[c] = sc; shift[c] = beta[c] - m * sc;
}

// ---------------- normalize + relu (bf16 -> bf16) ----------------
__global__ void k_bnrelu(const u16* __restrict__ Y, const float* __restrict__ scale,
                         const float* __restrict__ shift, u16* __restrict__ X2) {
    __shared__ float sc[256], sh[256];
    int t = threadIdx.x;
    sc[t] = scale[t]; sh[t] = shift[t];
    __syncthreads();
    size_t i = ((size_t)blockIdx.x * 256 + t) * 8;
    int c = (int)(i & 255);
    u16x8 v = *(const u16x8*)(Y + i);
    u16x8 o;
    #pragma unroll
    for (int k = 0; k < 8; ++k) {
        float f = fmaxf(sc[c + k] * bf2f(v[k]) + sh[c + k], 0.f);
        o[k] = f2bf(f);
    }
    *(u16x8*)(X2 + i) = o;
}

// ---------------- final: normalize + relu + transpose to [B][256][N] f32 ----------------
__global__ void k_final(const u16* __restrict__ Y2, const float* __restrict__ scale,
                        const float* __restrict__ shift, float* __restrict__ out) {
    int b = blockIdx.y, n0 = blockIdx.x * 64;
    __shared__ u16 tile[64 * 256];
    __shared__ float sc[256], sh[256];
    int t = threadIdx.x;
    sc[t] = scale[t]; sh[t] = shift[t];
    #pragma unroll
    for (int p = 0; p < 8; ++p) {
        int r = p * 8 + (t >> 5); int o = t & 31;
        u16x8 v = *(const u16x8*)(Y2 + ((size_t)(b * NN + n0 + r)) * CH + o * 8);
        int osw = o ^ (r & 7);                       // oct-XOR swizzle (keeps 16B alignment)
        *(u16x8*)&tile[r * 256 + osw * 8] = v;
    }
    __syncthreads();
    for (int p = 0; p < 64; ++p) {
        int c = p * 4 + (t >> 6); int n = t & 63;
        int osw = (c >> 3) ^ (n & 7);
        float f = bf2f(tile[n * 256 + osw * 8 + (c & 7)]);
        out[((size_t)(b * CH + c)) * NN + n0 + n] = fmaxf(sc[c] * f + sh[c], 0.f);
    }
}

extern "C" void kernel_launch(void* const* d_in, const int* in_sizes, int n_in,
                              void* d_out, int out_size, void* d_ws, size_t ws_size,
                              hipStream_t stream) {
    const float* f1  = (const float*)d_in[0];
    const float* c1  = (const float*)d_in[1];
    const float* f2  = (const float*)d_in[2];
    const float* c2  = (const float*)d_in[3];
    const float* W1  = (const float*)d_in[4];
    const float* b1  = (const float*)d_in[5];
    const float* g1  = (const float*)d_in[6];
    const float* be1 = (const float*)d_in[7];
    const float* W2  = (const float*)d_in[8];
    const float* b2  = (const float*)d_in[9];
    const float* g2  = (const float*)d_in[10];
    const float* be2 = (const float*)d_in[11];
    float* out = (float*)d_out;
    char* ws = (char*)d_ws;

    u16* Xp    = (u16*)(ws);                    // [65536][384] bf16 = 50,331,648 B
    u16* Y1p   = (u16*)(ws + 50331648);         // [65536][256] bf16 = 33,554,432 B
    u16* X2p   = Xp;                            // reuse (Xp dead after GEMM1)
    u16* Y2p   = Y1p;                           // reuse (Y1p dead after bnrelu)
    u16* W1b   = (u16*)(ws + 83886080);         // 196,608 B
    u16* W2b   = (u16*)(ws + 84082688);         // 131,072 B
    u16* F2t   = (u16*)(ws + 84213760);         // 8,388,608 B
    int*  idxo = (int*)(ws + 92602368);         // 786,432 B
    float* wo  = (float*)(ws + 93388800);       // 786,432 B
    float* stats = (float*)(ws + 94175232);     // 8,192 B
    float* S1a = stats,        *S2a = stats + 256;
    float* S1b = stats + 512,  *S2b = stats + 768;
    float* sc1 = stats + 1024, *sh1 = stats + 1280;
    float* sc2 = stats + 1536, *sh2 = stats + 1792;

    hipMemsetAsync(stats, 0, 4096, stream);
    k_convw<<<640, 256, 0, stream>>>(W1, W2, W1b, W2b);
    k_f2t<<<dim3(16, 4, 16), 256, 0, stream>>>(f2, F2t);
    k_knn<<<dim3(64, 16), 256, 0, stream>>>(c1, c2, idxo, wo);
    k_pack<<<dim3(64, 16), 256, 0, stream>>>(f1, F2t, idxo, wo, Xp);
    k_gemm<CIN><<<dim3(32, 2, 16), 256, 0, stream>>>(W1b, Xp, b1, Y1p, S1a, S2a);
    k_fin<<<1, 256, 0, stream>>>(S1a, S2a, g1, be1, sc1, sh1);
    k_bnrelu<<<8192, 256, 0, stream>>>(Y1p, sc1, sh1, X2p);
    k_gemm<CH><<<dim3(32, 2, 16), 256, 0, stream>>>(W2b, X2p, b2, Y2p, S1b, S2b);
    k_fin<<<1, 256, 0, stream>>>(S1b, S2b, g2, be2, sc2, sh2);
    k_final<<<dim3(64, 16), 256, 0, stream>>>(Y2p, sc2, sh2, out);
}

// Round 9
// 273.975 us; speedup vs baseline: 1.0666x; 1.0666x over previous
//
#include <hip/hip_runtime.h>

#define DEVI __device__ __forceinline__

typedef unsigned short u16;
typedef unsigned int   u32;
typedef u16  u16x8 __attribute__((ext_vector_type(8)));
typedef u16  u16x4 __attribute__((ext_vector_type(4)));
typedef short bf16x8 __attribute__((ext_vector_type(8)));
typedef float f32x4 __attribute__((ext_vector_type(4)));

static constexpr int BB = 16, NN = 4096, GG = 1024;
static constexpr int D1 = 128, D2 = 256, CIN = 384, CH = 256;

DEVI float bf2f(u16 h) { u32 u = ((u32)h) << 16; float f; __builtin_memcpy(&f, &u, 4); return f; }
DEVI u16 f2bf(float f) {
    u32 u; __builtin_memcpy(&u, &f, 4);
    u32 r = (u + 0x7fffu + ((u >> 16) & 1u)) >> 16;
    return (u16)r;
}

DEVI void gload16(const void* g, void* l) {
    __builtin_amdgcn_global_load_lds((const __attribute__((address_space(1))) void*)g,
                                     (__attribute__((address_space(3))) void*)l, 16, 0, 0);
}

// ---------------- weight conversion fp32 -> bf16 ----------------
__global__ void k_convw(const float* __restrict__ W1, const float* __restrict__ W2,
                        u16* __restrict__ W1b, u16* __restrict__ W2b) {
    int i = blockIdx.x * 256 + threadIdx.x;
    if (i < CH * CIN) W1b[i] = f2bf(W1[i]);
    int j = i - CH * CIN;
    if (j >= 0 && j < CH * CH) W2b[j] = f2bf(W2[j]);
}

// ---------------- feature2 transpose: [B][256][1024] f32 -> [B][1024][256] bf16 ----------------
__global__ void k_f2t(const float* __restrict__ f2, u16* __restrict__ f2t) {
    int b = blockIdx.z, ct = blockIdx.y, gt = blockIdx.x;
    __shared__ u16 tile[64][65];
    int t = threadIdx.x; int g = t & 63; int q = t >> 6;
    for (int p = 0; p < 16; ++p) {
        int cl = p * 4 + q;
        tile[g][cl] = f2bf(f2[((size_t)(b * D2 + ct * 64 + cl)) * GG + gt * 64 + g]);
    }
    __syncthreads();
    for (int p = 0; p < 16; ++p) {
        int gl = p * 4 + q;
        f2t[((size_t)(b * GG + gt * 64 + gl)) * D2 + ct * 64 + g] = tile[gl][g];
    }
}

// ---------------- 3-NN: 4 threads/query, packed-key min/max top-4 scan, fp64 re-rank of 16 ----------------
// key = (float_bits(d) & ~1023) | g : d>=0 so uint order == float order; idx embedded
// (unique keys, ties -> smaller idx). Sorted-insert via 7 v_min_u32/v_max_u32, no cndmask.
__global__ __launch_bounds__(256) void k_knn(const float* __restrict__ c1, const float* __restrict__ c2,
                                             int* __restrict__ idxo, float* __restrict__ wo) {
    int b = blockIdx.y; int t = threadIdx.x;
    int q = t >> 2, s = t & 3;
    int n = blockIdx.x * 64 + q;
    __shared__ float4 sp[GG];
    __shared__ u32 mi[256][4];
    const float* cb = c2 + (size_t)b * 3 * GG;
    for (int i = t; i < GG; i += 256) {
        float x = cb[i], y = cb[GG + i], z = cb[2 * GG + i];
        sp[i] = make_float4(x, y, z, x * x + y * y + z * z);
    }
    __syncthreads();
    const float* pb = c1 + (size_t)b * 3 * NN;
    float px = pb[n], py = pb[NN + n], pz = pb[2 * NN + n];
    float pn = px * px + py * py + pz * pz;
    u32 k0 = 0xFFFFFFFFu, k1 = 0xFFFFFFFFu, k2 = 0xFFFFFFFFu, k3 = 0xFFFFFFFFu;
    for (int gb = 0; gb < GG; gb += 16) {
        #pragma unroll
        for (int u = 0; u < 4; ++u) {
            int g = gb + u * 4 + s;
            float4 p = sp[g];
            float dot = px * p.x + py * p.y + pz * p.z;
            float d = fmaxf(pn + p.w - 2.f * dot, 0.f);
            u32 bits; __builtin_memcpy(&bits, &d, 4);
            u32 key = (bits & 0xFFFFFC00u) | (u32)g;
            u32 u0 = max(k0, key); k0 = min(k0, key);
            u32 u1 = max(k1, u0);  k1 = min(k1, u0);
            u32 u2 = max(k2, u1);  k2 = min(k2, u1);
            k3 = min(k3, u2);
        }
    }
    mi[t][0] = k0; mi[t][1] = k1; mi[t][2] = k2; mi[t][3] = k3;
    __syncthreads();
    if (s == 0) {
        // lexicographic (dist, idx) streaming top-3 over the 16 candidates, fp64
        double e0 = 1e300, e1 = 1e300, e2 = 1e300;
        int j0 = 0x7fffffff, j1 = 0x7fffffff, j2 = 0x7fffffff;
        #pragma unroll 4
        for (int k = 0; k < 16; ++k) {
            int g = (int)(mi[q * 4 + (k >> 2)][k & 3] & 1023u);
            float4 p = sp[g];
            double dx = (double)px - (double)p.x;
            double dy = (double)py - (double)p.y;
            double dz = (double)pz - (double)p.z;
            double d = dx * dx + dy * dy + dz * dz;
            bool lt2 = d < e2 || (d == e2 && g < j2);
            if (lt2) {
                bool lt1 = d < e1 || (d == e1 && g < j1);
                if (lt1) {
                    e2 = e1; j2 = j1;
                    bool lt0 = d < e0 || (d == e0 && g < j0);
                    if (lt0) { e1 = e0; j1 = j0; e0 = d; j0 = g; }
                    else { e1 = d; j1 = g; }
                } else { e2 = d; j2 = g; }
            }
        }
        float r0 = 1.f / ((float)e0 + 1e-8f);
        float r1 = 1.f / ((float)e1 + 1e-8f);
        float r2 = 1.f / ((float)e2 + 1e-8f);
        float sum = r0 + r1 + r2;
        size_t base = ((size_t)b * NN + n) * 3;
        idxo[base] = j0; idxo[base + 1] = j1; idxo[base + 2] = j2;
        wo[base] = r0 / sum; wo[base + 1] = r1 / sum; wo[base + 2] = r2 / sum;
    }
}

// ---------------- build X [B*N][384] bf16: cols 0..127 = feature1^T, 128..383 = interp ----------------
__global__ void k_pack(const float* __restrict__ f1, const u16* __restrict__ f2t,
                       const int* __restrict__ idxo, const float* __restrict__ wo,
                       u16* __restrict__ Xp) {
    int b = blockIdx.y; int n0 = blockIdx.x * 64;
    __shared__ u16 Xt[64][392];          // 384 + 8 pad (row stride 784 B = 49*16 -> aligned, conflict-light)
    int t = threadIdx.x; int j = t & 63; int q = t >> 6;
    // feature1 part
    for (int p = 0; p < 4; ++p) {
        int oct = p * 4 + q; int cb = oct * 8;
        u16x8 o;
        #pragma unroll
        for (int k = 0; k < 8; ++k)
            o[k] = f2bf(f1[((size_t)(b * D1 + cb + k)) * NN + n0 + j]);
        *(u16x8*)&Xt[j][cb] = o;
    }
    // interp part
    size_t bn = (size_t)b * NN + n0 + j;
    int g0 = idxo[bn * 3], g1 = idxo[bn * 3 + 1], g2 = idxo[bn * 3 + 2];
    float w0 = wo[bn * 3], w1 = wo[bn * 3 + 1], w2 = wo[bn * 3 + 2];
    const u16* r0 = f2t + ((size_t)b * GG + g0) * D2;
    const u16* r1 = f2t + ((size_t)b * GG + g1) * D2;
    const u16* r2 = f2t + ((size_t)b * GG + g2) * D2;
    for (int p = 0; p < 8; ++p) {
        int oct = p * 4 + q; int cb = oct * 8;
        u16x8 a = *(const u16x8*)(r0 + cb);
        u16x8 bb = *(const u16x8*)(r1 + cb);
        u16x8 cc = *(const u16x8*)(r2 + cb);
        u16x8 o;
        #pragma unroll
        for (int k = 0; k < 8; ++k)
            o[k] = f2bf(w0 * bf2f(a[k]) + w1 * bf2f(bb[k]) + w2 * bf2f(cc[k]));
        *(u16x8*)&Xt[j][D1 + cb] = o;
    }
    __syncthreads();
    // linear copy-out (global side is fully contiguous)
    u16* dst = Xp + ((size_t)b * NN + n0) * CIN;
    for (int p = 0; p < 12; ++p) {
        int ci = p * 256 + t;           // 0..3071 chunks of 8 u16
        int row = ci / 48, ch = ci % 48;
        *(u16x8*)(dst + (size_t)ci * 8) = *(const u16x8*)&Xt[row][ch * 8];
    }
}

// ---------------- GEMM: Y[n][c] (bf16) = A[256][K] * X[n][K]^T + bias, fused BN stats ----------------
// Double-buffered LDS staging (integer offsets into one smem block — no LDS
// pointer arrays, which hipcc rejects as static addrspacecast initializers);
// epilogue reuses the 32KB staging space as a swizzled 128x128 bf16 C-tile
// so global stores are full-line coalesced.
template<int K>
__global__ __launch_bounds__(256) void k_gemm(const u16* __restrict__ A, const u16* __restrict__ Bm,
                                              const float* __restrict__ bias, u16* __restrict__ Yp,
                                              float* __restrict__ S1, float* __restrict__ S2) {
    constexpr int NK = K / 32;
    int nt = blockIdx.x, mt = blockIdx.y, b = blockIdx.z;
    int c0 = mt * 128; size_t n0 = (size_t)b * NN + nt * 128;
    __shared__ u16 smem[16384];          // Al0|Al1|Bl0|Bl1 (4K u16 each); epilogue: 128x128 C-tile
    __shared__ float sred[4][64], qred[4][64];
    int t = threadIdx.x, lane = t & 63, w = t >> 6;
    int wr = w >> 1, wc = w & 1;
    f32x4 acc[4][4];
    #pragma unroll
    for (int m = 0; m < 4; ++m)
        #pragma unroll
        for (int n = 0; n < 4; ++n) acc[m][n] = (f32x4){0.f, 0.f, 0.f, 0.f};
    int lr = w * 32 + (lane >> 2);
    int lc = (lane & 3) * 8;

    // prologue: stage K-step 0 into buffer 0
    #pragma unroll
    for (int i = 0; i < 2; ++i) {
        gload16(A + (size_t)(c0 + lr + i * 16) * K + lc, &smem[(w * 32 + i * 16) * 32]);
        gload16(Bm + (n0 + lr + i * 16) * K + lc, &smem[8192 + (w * 32 + i * 16) * 32]);
    }
    __syncthreads();

    for (int ks = 0; ks < NK; ++ks) {
        int cur = ks & 1;
        int an = 4096 * (cur ^ 1), bn2 = 8192 + 4096 * (cur ^ 1);
        int ac = 4096 * cur,       bc  = 8192 + 4096 * cur;
        if (ks + 1 < NK) {
            #pragma unroll
            for (int i = 0; i < 2; ++i) {
                gload16(A + (size_t)(c0 + lr + i * 16) * K + (ks + 1) * 32 + lc, &smem[an + (w * 32 + i * 16) * 32]);
                gload16(Bm + (n0 + lr + i * 16) * K + (ks + 1) * 32 + lc, &smem[bn2 + (w * 32 + i * 16) * 32]);
            }
        }
        bf16x8 af[4], bfr[4];
        #pragma unroll
        for (int m = 0; m < 4; ++m)
            af[m] = *(const bf16x8*)&smem[ac + (wr * 64 + m * 16 + (lane & 15)) * 32 + (lane >> 4) * 8];
        #pragma unroll
        for (int n = 0; n < 4; ++n)
            bfr[n] = *(const bf16x8*)&smem[bc + (wc * 64 + n * 16 + (lane & 15)) * 32 + (lane >> 4) * 8];
        #pragma unroll
        for (int m = 0; m < 4; ++m)
            #pragma unroll
            for (int n = 0; n < 4; ++n)
                acc[m][n] = __builtin_amdgcn_mfma_f32_16x16x32_bf16(af[m], bfr[n], acc[m][n], 0, 0, 0);
        __syncthreads();
    }
    // epilogue: bias + bf16 -> swizzled LDS C-tile + per-channel partial sums (fp32 y, y^2)
    float sacc[4][4], qacc[4][4];
    #pragma unroll
    for (int m = 0; m < 4; ++m) {
        int c = c0 + wr * 64 + m * 16 + (lane >> 4) * 4;
        int clocal = wr * 64 + m * 16 + (lane >> 4) * 4;
        float b0 = bias[c], b1 = bias[c + 1], b2 = bias[c + 2], b3 = bias[c + 3];
        #pragma unroll
        for (int j = 0; j < 4; ++j) { sacc[m][j] = 0.f; qacc[m][j] = 0.f; }
        #pragma unroll
        for (int n = 0; n < 4; ++n) {
            int r = wc * 64 + n * 16 + (lane & 15);      // local row (n-index)
            f32x4 v = acc[m][n];
            float y0 = v[0] + b0, y1 = v[1] + b1, y2 = v[2] + b2, y3 = v[3] + b3;
            u16x4 o;
            o[0] = f2bf(y0); o[1] = f2bf(y1); o[2] = f2bf(y2); o[3] = f2bf(y3);
            *(u16x4*)&smem[r * 128 + (clocal ^ ((r & 7) << 3))] = o;   // swizzled ds_write_b64
            sacc[m][0] += y0; qacc[m][0] += y0 * y0;
            sacc[m][1] += y1; qacc[m][1] += y1 * y1;
            sacc[m][2] += y2; qacc[m][2] += y2 * y2;
            sacc[m][3] += y3; qacc[m][3] += y3 * y3;
        }
    }
    // reduce across the 16 lane-columns (bits 0..3 of lane; bits 4..5 = channel group)
    #pragma unroll
    for (int m = 0; m < 4; ++m)
        #pragma unroll
        for (int j = 0; j < 4; ++j) {
            float s = sacc[m][j], qv = qacc[m][j];
            #pragma unroll
            for (int mask = 1; mask <= 8; mask <<= 1) {
                s  += __shfl_xor(s, mask);
                qv += __shfl_xor(qv, mask);
            }
            sacc[m][j] = s; qacc[m][j] = qv;
        }
    int g = lane >> 4;
    if ((lane & 15) == 0) {
        #pragma unroll
        for (int m = 0; m < 4; ++m)
            #pragma unroll
            for (int j = 0; j < 4; ++j) {
                sred[w][m * 16 + g * 4 + j] = sacc[m][j];
                qred[w][m * 16 + g * 4 + j] = qacc[m][j];
            }
    }
    __syncthreads();
    // coalesced C-tile writeout: 16 lanes cover one full 256B row segment
    #pragma unroll
    for (int p = 0; p < 8; ++p) {
        int r = p * 16 + (t >> 4);
        int chunk = t & 15;
        u16x8 v = *(const u16x8*)&smem[r * 128 + ((chunk * 8) ^ ((r & 7) << 3))];
        *(u16x8*)(Yp + (n0 + r) * CH + c0 + chunk * 8) = v;
    }
    if (t < 128) {
        int half = t >> 6, cl = t & 63;
        float s  = sred[half * 2][cl] + sred[half * 2 + 1][cl];
        float qv = qred[half * 2][cl] + qred[half * 2 + 1][cl];
        atomicAdd(&S1[c0 + half * 64 + cl], s);
        atomicAdd(&S2[c0 + half * 64 + cl], qv);
    }
}

// ---------------- finalize BN scale/shift ----------------
__global__ void k_fin(const float* __restrict__ S1, const float* __restrict__ S2,
                      const float* __restrict__ gamma, const float* __restrict__ beta,
                      float* __restrict__ scale, float* __restrict__ shift) {
    int c = threadIdx.x;
    float inv = 1.f / 65536.f;
    float m = S1[c] * inv;
    float v = S2[c] * inv - m * m;
    float sc = gamma[c] * rsqrtf(v + 1e-5f);
    scale[c] = sc; shift[c] = beta[c] - m * sc;
}

// ---------------- normalize + relu (bf16 -> bf16) ----------------
__global__ void k_bnrelu(const u16* __restrict__ Y, const float* __restrict__ scale,
                         const float* __restrict__ shift, u16* __restrict__ X2) {
    __shared__ float sc[256], sh[256];
    int t = threadIdx.x;
    sc[t] = scale[t]; sh[t] = shift[t];
    __syncthreads();
    size_t i = ((size_t)blockIdx.x * 256 + t) * 8;
    int c = (int)(i & 255);
    u16x8 v = *(const u16x8*)(Y + i);
    u16x8 o;
    #pragma unroll
    for (int k = 0; k < 8; ++k) {
        float f = fmaxf(sc[c + k] * bf2f(v[k]) + sh[c + k], 0.f);
        o[k] = f2bf(f);
    }
    *(u16x8*)(X2 + i) = o;
}

// ---------------- final: normalize + relu + transpose to [B][256][N] f32 ----------------
__global__ void k_final(const u16* __restrict__ Y2, const float* __restrict__ scale,
                        const float* __restrict__ shift, float* __restrict__ out) {
    int b = blockIdx.y, n0 = blockIdx.x * 64;
    __shared__ u16 tile[64 * 256];
    __shared__ float sc[256], sh[256];
    int t = threadIdx.x;
    sc[t] = scale[t]; sh[t] = shift[t];
    #pragma unroll
    for (int p = 0; p < 8; ++p) {
        int r = p * 8 + (t >> 5); int o = t & 31;
        u16x8 v = *(const u16x8*)(Y2 + ((size_t)(b * NN + n0 + r)) * CH + o * 8);
        int osw = o ^ (r & 7);                       // oct-XOR swizzle (keeps 16B alignment)
        *(u16x8*)&tile[r * 256 + osw * 8] = v;
    }
    __syncthreads();
    for (int p = 0; p < 64; ++p) {
        int c = p * 4 + (t >> 6); int n = t & 63;
        int osw = (c >> 3) ^ (n & 7);
        float f = bf2f(tile[n * 256 + osw * 8 + (c & 7)]);
        out[((size_t)(b * CH + c)) * NN + n0 + n] = fmaxf(sc[c] * f + sh[c], 0.f);
    }
}

extern "C" void kernel_launch(void* const* d_in, const int* in_sizes, int n_in,
                              void* d_out, int out_size, void* d_ws, size_t ws_size,
                              hipStream_t stream) {
    const float* f1  = (const float*)d_in[0];
    const float* c1  = (const float*)d_in[1];
    const float* f2  = (const float*)d_in[2];
    const float* c2  = (const float*)d_in[3];
    const float* W1  = (const float*)d_in[4];
    const float* b1  = (const float*)d_in[5];
    const float* g1  = (const float*)d_in[6];
    const float* be1 = (const float*)d_in[7];
    const float* W2  = (const float*)d_in[8];
    const float* b2  = (const float*)d_in[9];
    const float* g2  = (const float*)d_in[10];
    const float* be2 = (const float*)d_in[11];
    float* out = (float*)d_out;
    char* ws = (char*)d_ws;

    u16* Xp    = (u16*)(ws);                    // [65536][384] bf16 = 50,331,648 B
    u16* Y1p   = (u16*)(ws + 50331648);         // [65536][256] bf16 = 33,554,432 B
    u16* X2p   = Xp;                            // reuse (Xp dead after GEMM1)
    u16* Y2p   = Y1p;                           // reuse (Y1p dead after bnrelu)
    u16* W1b   = (u16*)(ws + 83886080);         // 196,608 B
    u16* W2b   = (u16*)(ws + 84082688);         // 131,072 B
    u16* F2t   = (u16*)(ws + 84213760);         // 8,388,608 B
    int*  idxo = (int*)(ws + 92602368);         // 786,432 B
    float* wo  = (float*)(ws + 93388800);       // 786,432 B
    float* stats = (float*)(ws + 94175232);     // 8,192 B
    float* S1a = stats,        *S2a = stats + 256;
    float* S1b = stats + 512,  *S2b = stats + 768;
    float* sc1 = stats + 1024, *sh1 = stats + 1280;
    float* sc2 = stats + 1536, *sh2 = stats + 1792;

    (void)hipMemsetAsync(stats, 0, 4096, stream);
    k_convw<<<640, 256, 0, stream>>>(W1, W2, W1b, W2b);
    k_f2t<<<dim3(16, 4, 16), 256, 0, stream>>>(f2, F2t);
    k_knn<<<dim3(64, 16), 256, 0, stream>>>(c1, c2, idxo, wo);
    k_pack<<<dim3(64, 16), 256, 0, stream>>>(f1, F2t, idxo, wo, Xp);
    k_gemm<CIN><<<dim3(32, 2, 16), 256, 0, stream>>>(W1b, Xp, b1, Y1p, S1a, S2a);
    k_fin<<<1, 256, 0, stream>>>(S1a, S2a, g1, be1, sc1, sh1);
    k_bnrelu<<<8192, 256, 0, stream>>>(Y1p, sc1, sh1, X2p);
    k_gemm<CH><<<dim3(32, 2, 16), 256, 0, stream>>>(W2b, X2p, b2, Y2p, S1b, S2b);
    k_fin<<<1, 256, 0, stream>>>(S1b, S2b, g2, be2, sc2, sh2);
    k_final<<<dim3(64, 16), 256, 0, stream>>>(Y2p, sc2, sh2, out);
}

// Round 10
// 268.444 us; speedup vs baseline: 1.0886x; 1.0206x over previous
//
#include <hip/hip_runtime.h>

#define DEVI __device__ __forceinline__

typedef unsigned short u16;
typedef unsigned int   u32;
typedef u16  u16x8 __attribute__((ext_vector_type(8)));
typedef u16  u16x4 __attribute__((ext_vector_type(4)));
typedef short bf16x8 __attribute__((ext_vector_type(8)));
typedef float f32x4 __attribute__((ext_vector_type(4)));

static constexpr int BB = 16, NN = 4096, GG = 1024;
static constexpr int D1 = 128, D2 = 256, CIN = 384, CH = 256;

DEVI float bf2f(u16 h) { u32 u = ((u32)h) << 16; float f; __builtin_memcpy(&f, &u, 4); return f; }
DEVI u16 f2bf(float f) {
    u32 u; __builtin_memcpy(&u, &f, 4);
    u32 r = (u + 0x7fffu + ((u >> 16) & 1u)) >> 16;
    return (u16)r;
}

DEVI void gload16(const void* g, void* l) {
    __builtin_amdgcn_global_load_lds((const __attribute__((address_space(1))) void*)g,
                                     (__attribute__((address_space(3))) void*)l, 16, 0, 0);
}

// ---------------- weight conversion fp32 -> bf16 ----------------
__global__ void k_convw(const float* __restrict__ W1, const float* __restrict__ W2,
                        u16* __restrict__ W1b, u16* __restrict__ W2b) {
    int i = blockIdx.x * 256 + threadIdx.x;
    if (i < CH * CIN) W1b[i] = f2bf(W1[i]);
    int j = i - CH * CIN;
    if (j >= 0 && j < CH * CH) W2b[j] = f2bf(W2[j]);
}

// ---------------- feature2 transpose: [B][256][1024] f32 -> [B][1024][256] bf16 ----------------
__global__ void k_f2t(const float* __restrict__ f2, u16* __restrict__ f2t) {
    int b = blockIdx.z, ct = blockIdx.y, gt = blockIdx.x;
    __shared__ u16 tile[64][65];
    int t = threadIdx.x; int g = t & 63; int q = t >> 6;
    for (int p = 0; p < 16; ++p) {
        int cl = p * 4 + q;
        tile[g][cl] = f2bf(f2[((size_t)(b * D2 + ct * 64 + cl)) * GG + gt * 64 + g]);
    }
    __syncthreads();
    for (int p = 0; p < 16; ++p) {
        int gl = p * 4 + q;
        f2t[((size_t)(b * GG + gt * 64 + gl)) * D2 + ct * 64 + g] = tile[gl][g];
    }
}

// ---------------- 3-NN: 8 threads/query, h-rank packed-key top-3 scan, fp64 re-rank of 24 ----------------
// h = |g|^2/2 - q.g is monotone in d (per query). Ordered-uint via sign-flip; idx in low
// 10 bits (ties -> smaller idx). Top-3/thread via 5 v_min_u32/v_max_u32. Global top-3 is
// contained in the union of per-thread top-3s; exact fp64 lexicographic re-rank of 24.
__global__ __launch_bounds__(512) void k_knn(const float* __restrict__ c1, const float* __restrict__ c2,
                                             int* __restrict__ idxo, float* __restrict__ wo) {
    int b = blockIdx.y; int t = threadIdx.x;
    int q = t >> 3, s = t & 7;
    int n = blockIdx.x * 64 + q;
    __shared__ float4 sp[GG];          // x, y, z, |.|^2 / 2
    __shared__ u32 mi[512][3];
    const float* cb = c2 + (size_t)b * 3 * GG;
    for (int i = t; i < GG; i += 512) {
        float x = cb[i], y = cb[GG + i], z = cb[2 * GG + i];
        sp[i] = make_float4(x, y, z, 0.5f * (x * x + y * y + z * z));
    }
    __syncthreads();
    const float* pb = c1 + (size_t)b * 3 * NN;
    float px = pb[n], py = pb[NN + n], pz = pb[2 * NN + n];
    float nx = -px, ny = -py, nz = -pz;
    u32 k0 = 0xFFFFFFFFu, k1 = 0xFFFFFFFFu, k2 = 0xFFFFFFFFu;
    for (int gb = 0; gb < GG; gb += 32) {
        #pragma unroll
        for (int u = 0; u < 4; ++u) {
            int g = gb + u * 8 + s;
            float4 p = sp[g];
            float h = fmaf(nx, p.x, fmaf(ny, p.y, fmaf(nz, p.z, p.w)));
            u32 bits; __builtin_memcpy(&bits, &h, 4);
            u32 flip = ((u32)((int)bits >> 31)) | 0x80000000u;
            u32 key = ((bits ^ flip) & 0xFFFFFC00u) | (u32)g;
            u32 u0 = max(k0, key); k0 = min(k0, key);
            u32 u1 = max(k1, u0);  k1 = min(k1, u0);
            k2 = min(k2, u1);
        }
    }
    mi[t][0] = k0; mi[t][1] = k1; mi[t][2] = k2;
    __syncthreads();
    if (s == 0) {
        // lexicographic (dist, idx) streaming top-3 over the 24 candidates, fp64
        double e0 = 1e300, e1 = 1e300, e2 = 1e300;
        int j0 = 0x7fffffff, j1 = 0x7fffffff, j2 = 0x7fffffff;
        #pragma unroll
        for (int tt = 0; tt < 8; ++tt)
        #pragma unroll
        for (int sl = 0; sl < 3; ++sl) {
            int g = (int)(mi[q * 8 + tt][sl] & 1023u);
            float4 p = sp[g];
            double dx = (double)px - (double)p.x;
            double dy = (double)py - (double)p.y;
            double dz = (double)pz - (double)p.z;
            double d = dx * dx + dy * dy + dz * dz;
            bool lt2 = d < e2 || (d == e2 && g < j2);
            if (lt2) {
                bool lt1 = d < e1 || (d == e1 && g < j1);
                if (lt1) {
                    e2 = e1; j2 = j1;
                    bool lt0 = d < e0 || (d == e0 && g < j0);
                    if (lt0) { e1 = e0; j1 = j0; e0 = d; j0 = g; }
                    else { e1 = d; j1 = g; }
                } else { e2 = d; j2 = g; }
            }
        }
        float r0 = 1.f / ((float)e0 + 1e-8f);
        float r1 = 1.f / ((float)e1 + 1e-8f);
        float r2 = 1.f / ((float)e2 + 1e-8f);
        float sum = r0 + r1 + r2;
        size_t base = ((size_t)b * NN + n) * 3;
        idxo[base] = j0; idxo[base + 1] = j1; idxo[base + 2] = j2;
        wo[base] = r0 / sum; wo[base + 1] = r1 / sum; wo[base + 2] = r2 / sum;
    }
}

// ---------------- build X [B*N][384] bf16: cols 0..127 = feature1^T, 128..383 = interp ----------------
__global__ void k_pack(const float* __restrict__ f1, const u16* __restrict__ f2t,
                       const int* __restrict__ idxo, const float* __restrict__ wo,
                       u16* __restrict__ Xp) {
    int b = blockIdx.y; int n0 = blockIdx.x * 64;
    __shared__ u16 Xt[64][392];          // 384 + 8 pad (row stride 784 B = 49*16 -> aligned, conflict-light)
    int t = threadIdx.x; int j = t & 63; int q = t >> 6;
    // feature1 part
    for (int p = 0; p < 4; ++p) {
        int oct = p * 4 + q; int cb = oct * 8;
        u16x8 o;
        #pragma unroll
        for (int k = 0; k < 8; ++k)
            o[k] = f2bf(f1[((size_t)(b * D1 + cb + k)) * NN + n0 + j]);
        *(u16x8*)&Xt[j][cb] = o;
    }
    // interp part
    size_t bn = (size_t)b * NN + n0 + j;
    int g0 = idxo[bn * 3], g1 = idxo[bn * 3 + 1], g2 = idxo[bn * 3 + 2];
    float w0 = wo[bn * 3], w1 = wo[bn * 3 + 1], w2 = wo[bn * 3 + 2];
    const u16* r0 = f2t + ((size_t)b * GG + g0) * D2;
    const u16* r1 = f2t + ((size_t)b * GG + g1) * D2;
    const u16* r2 = f2t + ((size_t)b * GG + g2) * D2;
    for (int p = 0; p < 8; ++p) {
        int oct = p * 4 + q; int cb = oct * 8;
        u16x8 a = *(const u16x8*)(r0 + cb);
        u16x8 bb = *(const u16x8*)(r1 + cb);
        u16x8 cc = *(const u16x8*)(r2 + cb);
        u16x8 o;
        #pragma unroll
        for (int k = 0; k < 8; ++k)
            o[k] = f2bf(w0 * bf2f(a[k]) + w1 * bf2f(bb[k]) + w2 * bf2f(cc[k]));
        *(u16x8*)&Xt[j][D1 + cb] = o;
    }
    __syncthreads();
    // linear copy-out (global side is fully contiguous)
    u16* dst = Xp + ((size_t)b * NN + n0) * CIN;
    for (int p = 0; p < 12; ++p) {
        int ci = p * 256 + t;           // 0..3071 chunks of 8 u16
        int row = ci / 48, ch = ci % 48;
        *(u16x8*)(dst + (size_t)ci * 8) = *(const u16x8*)&Xt[row][ch * 8];
    }
}

// ---------------- GEMM: Y[n][c] (bf16) = A[256][K] * X[n][K]^T + bias, fused BN stats ----------------
// Double-buffered LDS staging (integer offsets into one smem block); epilogue reuses the
// 32KB staging space as a swizzled 128x128 bf16 C-tile so global stores are full-line coalesced.
template<int K>
__global__ __launch_bounds__(256) void k_gemm(const u16* __restrict__ A, const u16* __restrict__ Bm,
                                              const float* __restrict__ bias, u16* __restrict__ Yp,
                                              float* __restrict__ S1, float* __restrict__ S2) {
    constexpr int NK = K / 32;
    int nt = blockIdx.x, mt = blockIdx.y, b = blockIdx.z;
    int c0 = mt * 128; size_t n0 = (size_t)b * NN + nt * 128;
    __shared__ u16 smem[16384];          // Al0|Al1|Bl0|Bl1 (4K u16 each); epilogue: 128x128 C-tile
    __shared__ float sred[4][64], qred[4][64];
    int t = threadIdx.x, lane = t & 63, w = t >> 6;
    int wr = w >> 1, wc = w & 1;
    f32x4 acc[4][4];
    #pragma unroll
    for (int m = 0; m < 4; ++m)
        #pragma unroll
        for (int n = 0; n < 4; ++n) acc[m][n] = (f32x4){0.f, 0.f, 0.f, 0.f};
    int lr = w * 32 + (lane >> 2);
    int lc = (lane & 3) * 8;

    // prologue: stage K-step 0 into buffer 0
    #pragma unroll
    for (int i = 0; i < 2; ++i) {
        gload16(A + (size_t)(c0 + lr + i * 16) * K + lc, &smem[(w * 32 + i * 16) * 32]);
        gload16(Bm + (n0 + lr + i * 16) * K + lc, &smem[8192 + (w * 32 + i * 16) * 32]);
    }
    __syncthreads();

    for (int ks = 0; ks < NK; ++ks) {
        int cur = ks & 1;
        int an = 4096 * (cur ^ 1), bn2 = 8192 + 4096 * (cur ^ 1);
        int ac = 4096 * cur,       bc  = 8192 + 4096 * cur;
        if (ks + 1 < NK) {
            #pragma unroll
            for (int i = 0; i < 2; ++i) {
                gload16(A + (size_t)(c0 + lr + i * 16) * K + (ks + 1) * 32 + lc, &smem[an + (w * 32 + i * 16) * 32]);
                gload16(Bm + (n0 + lr + i * 16) * K + (ks + 1) * 32 + lc, &smem[bn2 + (w * 32 + i * 16) * 32]);
            }
        }
        bf16x8 af[4], bfr[4];
        #pragma unroll
        for (int m = 0; m < 4; ++m)
            af[m] = *(const bf16x8*)&smem[ac + (wr * 64 + m * 16 + (lane & 15)) * 32 + (lane >> 4) * 8];
        #pragma unroll
        for (int n = 0; n < 4; ++n)
            bfr[n] = *(const bf16x8*)&smem[bc + (wc * 64 + n * 16 + (lane & 15)) * 32 + (lane >> 4) * 8];
        #pragma unroll
        for (int m = 0; m < 4; ++m)
            #pragma unroll
            for (int n = 0; n < 4; ++n)
                acc[m][n] = __builtin_amdgcn_mfma_f32_16x16x32_bf16(af[m], bfr[n], acc[m][n], 0, 0, 0);
        __syncthreads();
    }
    // epilogue: bias + bf16 -> swizzled LDS C-tile + per-channel partial sums (fp32 y, y^2)
    float sacc[4][4], qacc[4][4];
    #pragma unroll
    for (int m = 0; m < 4; ++m) {
        int c = c0 + wr * 64 + m * 16 + (lane >> 4) * 4;
        int clocal = wr * 64 + m * 16 + (lane >> 4) * 4;
        float b0 = bias[c], b1 = bias[c + 1], b2 = bias[c + 2], b3 = bias[c + 3];
        #pragma unroll
        for (int j = 0; j < 4; ++j) { sacc[m][j] = 0.f; qacc[m][j] = 0.f; }
        #pragma unroll
        for (int n = 0; n < 4; ++n) {
            int r = wc * 64 + n * 16 + (lane & 15);      // local row (n-index)
            f32x4 v = acc[m][n];
            float y0 = v[0] + b0, y1 = v[1] + b1, y2 = v[2] + b2, y3 = v[3] + b3;
            u16x4 o;
            o[0] = f2bf(y0); o[1] = f2bf(y1); o[2] = f2bf(y2); o[3] = f2bf(y3);
            *(u16x4*)&smem[r * 128 + (clocal ^ ((r & 7) << 3))] = o;   // swizzled ds_write_b64
            sacc[m][0] += y0; qacc[m][0] += y0 * y0;
            sacc[m][1] += y1; qacc[m][1] += y1 * y1;
            sacc[m][2] += y2; qacc[m][2] += y2 * y2;
            sacc[m][3] += y3; qacc[m][3] += y3 * y3;
        }
    }
    // reduce across the 16 lane-columns (bits 0..3 of lane; bits 4..5 = channel group)
    #pragma unroll
    for (int m = 0; m < 4; ++m)
        #pragma unroll
        for (int j = 0; j < 4; ++j) {
            float s = sacc[m][j], qv = qacc[m][j];
            #pragma unroll
            for (int mask = 1; mask <= 8; mask <<= 1) {
                s  += __shfl_xor(s, mask);
                qv += __shfl_xor(qv, mask);
            }
            sacc[m][j] = s; qacc[m][j] = qv;
        }
    int g = lane >> 4;
    if ((lane & 15) == 0) {
        #pragma unroll
        for (int m = 0; m < 4; ++m)
            #pragma unroll
            for (int j = 0; j < 4; ++j) {
                sred[w][m * 16 + g * 4 + j] = sacc[m][j];
                qred[w][m * 16 + g * 4 + j] = qacc[m][j];
            }
    }
    __syncthreads();
    // coalesced C-tile writeout: 16 lanes cover one full 256B row segment
    #pragma unroll
    for (int p = 0; p < 8; ++p) {
        int r = p * 16 + (t >> 4);
        int chunk = t & 15;
        u16x8 v = *(const u16x8*)&smem[r * 128 + ((chunk * 8) ^ ((r & 7) << 3))];
        *(u16x8*)(Yp + (n0 + r) * CH + c0 + chunk * 8) = v;
    }
    if (t < 128) {
        int half = t >> 6, cl = t & 63;
        float s  = sred[half * 2][cl] + sred[half * 2 + 1][cl];
        float qv = qred[half * 2][cl] + qred[half * 2 + 1][cl];
        atomicAdd(&S1[c0 + half * 64 + cl], s);
        atomicAdd(&S2[c0 + half * 64 + cl], qv);
    }
}

// ---------------- normalize + relu (bf16 -> bf16), BN finalize folded in ----------------
__global__ void k_bnrelu(const u16* __restrict__ Y, const float* __restrict__ S1,
                         const float* __restrict__ S2, const float* __restrict__ gamma,
                         const float* __restrict__ beta, u16* __restrict__ X2) {
    __shared__ float sc[256], sh[256];
    int t = threadIdx.x;
    {
        float inv = 1.f / 65536.f;
        float m = S1[t] * inv;
        float v = S2[t] * inv - m * m;
        float s = gamma[t] * rsqrtf(v + 1e-5f);
        sc[t] = s; sh[t] = beta[t] - m * s;
    }
    __syncthreads();
    size_t i = ((size_t)blockIdx.x * 256 + t) * 8;
    int c = (int)(i & 255);
    u16x8 v = *(const u16x8*)(Y + i);
    u16x8 o;
    #pragma unroll
    for (int k = 0; k < 8; ++k) {
        float f = fmaxf(sc[c + k] * bf2f(v[k]) + sh[c + k], 0.f);
        o[k] = f2bf(f);
    }
    *(u16x8*)(X2 + i) = o;
}

// ---------------- final: normalize + relu + transpose to [B][256][N] f32, finalize folded ----------------
__global__ void k_final(const u16* __restrict__ Y2, const float* __restrict__ S1,
                        const float* __restrict__ S2, const float* __restrict__ gamma,
                        const float* __restrict__ beta, float* __restrict__ out) {
    int b = blockIdx.y, n0 = blockIdx.x * 64;
    __shared__ u16 tile[64 * 256];
    __shared__ float sc[256], sh[256];
    int t = threadIdx.x;
    {
        float inv = 1.f / 65536.f;
        float m = S1[t] * inv;
        float v = S2[t] * inv - m * m;
        float s = gamma[t] * rsqrtf(v + 1e-5f);
        sc[t] = s; sh[t] = beta[t] - m * s;
    }
    #pragma unroll
    for (int p = 0; p < 8; ++p) {
        int r = p * 8 + (t >> 5); int o = t & 31;
        u16x8 v = *(const u16x8*)(Y2 + ((size_t)(b * NN + n0 + r)) * CH + o * 8);
        int osw = o ^ (r & 7);                       // oct-XOR swizzle (keeps 16B alignment)
        *(u16x8*)&tile[r * 256 + osw * 8] = v;
    }
    __syncthreads();
    for (int p = 0; p < 64; ++p) {
        int c = p * 4 + (t >> 6); int n = t & 63;
        int osw = (c >> 3) ^ (n & 7);
        float f = bf2f(tile[n * 256 + osw * 8 + (c & 7)]);
        out[((size_t)(b * CH + c)) * NN + n0 + n] = fmaxf(sc[c] * f + sh[c], 0.f);
    }
}

extern "C" void kernel_launch(void* const* d_in, const int* in_sizes, int n_in,
                              void* d_out, int out_size, void* d_ws, size_t ws_size,
                              hipStream_t stream) {
    const float* f1  = (const float*)d_in[0];
    const float* c1  = (const float*)d_in[1];
    const float* f2  = (const float*)d_in[2];
    const float* c2  = (const float*)d_in[3];
    const float* W1  = (const float*)d_in[4];
    const float* b1  = (const float*)d_in[5];
    const float* g1  = (const float*)d_in[6];
    const float* be1 = (const float*)d_in[7];
    const float* W2  = (const float*)d_in[8];
    const float* b2  = (const float*)d_in[9];
    const float* g2  = (const float*)d_in[10];
    const float* be2 = (const float*)d_in[11];
    float* out = (float*)d_out;
    char* ws = (char*)d_ws;

    u16* Xp    = (u16*)(ws);                    // [65536][384] bf16 = 50,331,648 B
    u16* Y1p   = (u16*)(ws + 50331648);         // [65536][256] bf16 = 33,554,432 B
    u16* X2p   = Xp;                            // reuse (Xp dead after GEMM1)
    u16* Y2p   = Y1p;                           // reuse (Y1p dead after bnrelu)
    u16* W1b   = (u16*)(ws + 83886080);         // 196,608 B
    u16* W2b   = (u16*)(ws + 84082688);         // 131,072 B
    u16* F2t   = (u16*)(ws + 84213760);         // 8,388,608 B
    int*  idxo = (int*)(ws + 92602368);         // 786,432 B
    float* wo  = (float*)(ws + 93388800);       // 786,432 B
    float* stats = (float*)(ws + 94175232);     // 8,192 B
    float* S1a = stats,        *S2a = stats + 256;
    float* S1b = stats + 512,  *S2b = stats + 768;

    (void)hipMemsetAsync(stats, 0, 4096, stream);
    k_convw<<<640, 256, 0, stream>>>(W1, W2, W1b, W2b);
    k_f2t<<<dim3(16, 4, 16), 256, 0, stream>>>(f2, F2t);
    k_knn<<<dim3(64, 16), 512, 0, stream>>>(c1, c2, idxo, wo);
    k_pack<<<dim3(64, 16), 256, 0, stream>>>(f1, F2t, idxo, wo, Xp);
    k_gemm<CIN><<<dim3(32, 2, 16), 256, 0, stream>>>(W1b, Xp, b1, Y1p, S1a, S2a);
    k_bnrelu<<<8192, 256, 0, stream>>>(Y1p, S1a, S2a, g1, be1, X2p);
    k_gemm<CH><<<dim3(32, 2, 16), 256, 0, stream>>>(W2b, X2p, b2, Y2p, S1b, S2b);
    k_final<<<dim3(64, 16), 256, 0, stream>>>(Y2p, S1b, S2b, g2, be2, out);
}

// Round 12
// 266.765 us; speedup vs baseline: 1.0954x; 1.0063x over previous
//
#include <hip/hip_runtime.h>

#define DEVI __device__ __forceinline__

typedef unsigned short u16;
typedef unsigned int   u32;
typedef u16  u16x8 __attribute__((ext_vector_type(8)));
typedef u16  u16x4 __attribute__((ext_vector_type(4)));
typedef short bf16x8 __attribute__((ext_vector_type(8)));
typedef float f32x4 __attribute__((ext_vector_type(4)));

static constexpr int BB = 16, NN = 4096, GG = 1024;
static constexpr int D1 = 128, D2 = 256, CIN = 384, CH = 256;

DEVI float bf2f(u16 h) { u32 u = ((u32)h) << 16; float f; __builtin_memcpy(&f, &u, 4); return f; }
DEVI u16 f2bf(float f) {
    u32 u; __builtin_memcpy(&u, &f, 4);
    u32 r = (u + 0x7fffu + ((u >> 16) & 1u)) >> 16;
    return (u16)r;
}

DEVI void gload16(const void* g, void* l) {
    __builtin_amdgcn_global_load_lds((const __attribute__((address_space(1))) void*)g,
                                     (__attribute__((address_space(3))) void*)l, 16, 0, 0);
}

// ---------------- weight conversion fp32 -> bf16 ----------------
__global__ void k_convw(const float* __restrict__ W1, const float* __restrict__ W2,
                        u16* __restrict__ W1b, u16* __restrict__ W2b) {
    int i = blockIdx.x * 256 + threadIdx.x;
    if (i < CH * CIN) W1b[i] = f2bf(W1[i]);
    int j = i - CH * CIN;
    if (j >= 0 && j < CH * CH) W2b[j] = f2bf(W2[j]);
}

// ---------------- feature2 transpose: [B][256][1024] f32 -> [B][1024][256] bf16 ----------------
__global__ void k_f2t(const float* __restrict__ f2, u16* __restrict__ f2t) {
    int b = blockIdx.z, ct = blockIdx.y, gt = blockIdx.x;
    __shared__ u16 tile[64][65];
    int t = threadIdx.x; int g = t & 63; int q = t >> 6;
    for (int p = 0; p < 16; ++p) {
        int cl = p * 4 + q;
        tile[g][cl] = f2bf(f2[((size_t)(b * D2 + ct * 64 + cl)) * GG + gt * 64 + g]);
    }
    __syncthreads();
    for (int p = 0; p < 16; ++p) {
        int gl = p * 4 + q;
        f2t[((size_t)(b * GG + gt * 64 + gl)) * D2 + ct * 64 + g] = tile[gl][g];
    }
}

// ---------------- 3-NN: 8 threads/query, h-rank packed-key top-3 scan, fp64 re-rank of 24 ----------------
__global__ __launch_bounds__(512) void k_knn(const float* __restrict__ c1, const float* __restrict__ c2,
                                             int* __restrict__ idxo, float* __restrict__ wo) {
    int b = blockIdx.y; int t = threadIdx.x;
    int q = t >> 3, s = t & 7;
    int n = blockIdx.x * 64 + q;
    __shared__ float4 sp[GG];          // x, y, z, |.|^2 / 2
    __shared__ u32 mi[512][3];
    const float* cb = c2 + (size_t)b * 3 * GG;
    for (int i = t; i < GG; i += 512) {
        float x = cb[i], y = cb[GG + i], z = cb[2 * GG + i];
        sp[i] = make_float4(x, y, z, 0.5f * (x * x + y * y + z * z));
    }
    __syncthreads();
    const float* pb = c1 + (size_t)b * 3 * NN;
    float px = pb[n], py = pb[NN + n], pz = pb[2 * NN + n];
    float nx = -px, ny = -py, nz = -pz;
    u32 k0 = 0xFFFFFFFFu, k1 = 0xFFFFFFFFu, k2 = 0xFFFFFFFFu;
    for (int gb = 0; gb < GG; gb += 32) {
        #pragma unroll
        for (int u = 0; u < 4; ++u) {
            int g = gb + u * 8 + s;
            float4 p = sp[g];
            float h = fmaf(nx, p.x, fmaf(ny, p.y, fmaf(nz, p.z, p.w)));
            u32 bits; __builtin_memcpy(&bits, &h, 4);
            u32 flip = ((u32)((int)bits >> 31)) | 0x80000000u;
            u32 key = ((bits ^ flip) & 0xFFFFFC00u) | (u32)g;
            u32 u0 = max(k0, key); k0 = min(k0, key);
            u32 u1 = max(k1, u0);  k1 = min(k1, u0);
            k2 = min(k2, u1);
        }
    }
    mi[t][0] = k0; mi[t][1] = k1; mi[t][2] = k2;
    __syncthreads();
    if (s == 0) {
        // lexicographic (dist, idx) streaming top-3 over the 24 candidates, fp64
        double e0 = 1e300, e1 = 1e300, e2 = 1e300;
        int j0 = 0x7fffffff, j1 = 0x7fffffff, j2 = 0x7fffffff;
        #pragma unroll
        for (int tt = 0; tt < 8; ++tt)
        #pragma unroll
        for (int sl = 0; sl < 3; ++sl) {
            int g = (int)(mi[q * 8 + tt][sl] & 1023u);
            float4 p = sp[g];
            double dx = (double)px - (double)p.x;
            double dy = (double)py - (double)p.y;
            double dz = (double)pz - (double)p.z;
            double d = dx * dx + dy * dy + dz * dz;
            bool lt2 = d < e2 || (d == e2 && g < j2);
            if (lt2) {
                bool lt1 = d < e1 || (d == e1 && g < j1);
                if (lt1) {
                    e2 = e1; j2 = j1;
                    bool lt0 = d < e0 || (d == e0 && g < j0);
                    if (lt0) { e1 = e0; j1 = j0; e0 = d; j0 = g; }
                    else { e1 = d; j1 = g; }
                } else { e2 = d; j2 = g; }
            }
        }
        float r0 = 1.f / ((float)e0 + 1e-8f);
        float r1 = 1.f / ((float)e1 + 1e-8f);
        float r2 = 1.f / ((float)e2 + 1e-8f);
        float sum = r0 + r1 + r2;
        size_t base = ((size_t)b * NN + n) * 3;
        idxo[base] = j0; idxo[base + 1] = j1; idxo[base + 2] = j2;
        wo[base] = r0 / sum; wo[base + 1] = r1 / sum; wo[base + 2] = r2 / sum;
    }
}

// ---------------- build X [B*N][384] bf16: cols 0..127 = feature1^T, 128..383 = interp ----------------
// 32 rows/block (25KB LDS -> 6 blocks/CU, 24 waves/CU; was 3 blocks at 50KB).
__global__ __launch_bounds__(256) void k_pack(const float* __restrict__ f1, const u16* __restrict__ f2t,
                                              const int* __restrict__ idxo, const float* __restrict__ wo,
                                              u16* __restrict__ Xp) {
    int b = blockIdx.y; int n0 = blockIdx.x * 32;
    __shared__ u16 Xt[32][392];          // 384 + 8 pad (row stride 784 B, 16B-aligned)
    int t = threadIdx.x; int j = t & 31; int q = t >> 5;   // 8 channel-workers per row
    // feature1 part: 16 chunks of 8 cols; each q does 2
    #pragma unroll
    for (int p = 0; p < 2; ++p) {
        int oct = p * 8 + q; int cb = oct * 8;
        u16x8 o;
        #pragma unroll
        for (int k = 0; k < 8; ++k)
            o[k] = f2bf(f1[((size_t)(b * D1 + cb + k)) * NN + n0 + j]);
        *(u16x8*)&Xt[j][cb] = o;
    }
    // interp part: 32 chunks of 8 cols; each q does 4
    size_t bn = (size_t)b * NN + n0 + j;
    int g0 = idxo[bn * 3], g1 = idxo[bn * 3 + 1], g2 = idxo[bn * 3 + 2];
    float w0 = wo[bn * 3], w1 = wo[bn * 3 + 1], w2 = wo[bn * 3 + 2];
    const u16* r0 = f2t + ((size_t)b * GG + g0) * D2;
    const u16* r1 = f2t + ((size_t)b * GG + g1) * D2;
    const u16* r2 = f2t + ((size_t)b * GG + g2) * D2;
    #pragma unroll
    for (int p = 0; p < 4; ++p) {
        int oct = p * 8 + q; int cb = oct * 8;
        u16x8 a = *(const u16x8*)(r0 + cb);
        u16x8 bb = *(const u16x8*)(r1 + cb);
        u16x8 cc = *(const u16x8*)(r2 + cb);
        u16x8 o;
        #pragma unroll
        for (int k = 0; k < 8; ++k)
            o[k] = f2bf(w0 * bf2f(a[k]) + w1 * bf2f(bb[k]) + w2 * bf2f(cc[k]));
        *(u16x8*)&Xt[j][D1 + cb] = o;
    }
    __syncthreads();
    // linear copy-out (global side fully contiguous): 32*384 u16 = 1536 chunks of 8
    u16* dst = Xp + ((size_t)b * NN + n0) * CIN;
    #pragma unroll
    for (int p = 0; p < 6; ++p) {
        int ci = p * 256 + t;
        int row = ci / 48, ch = ci % 48;
        *(u16x8*)(dst + (size_t)ci * 8) = *(const u16x8*)&Xt[row][ch * 8];
    }
}

// ---------------- GEMM: Y[n][c] (bf16) = A[256][K] * X[n][K]^T + bias, fused BN stats ----------------
// Double-buffered LDS staging (integer offsets into one smem block); epilogue reuses the
// 32KB staging space as a swizzled 128x128 bf16 C-tile so global stores are full-line coalesced.
template<int K>
__global__ __launch_bounds__(256) void k_gemm(const u16* __restrict__ A, const u16* __restrict__ Bm,
                                              const float* __restrict__ bias, u16* __restrict__ Yp,
                                              float* __restrict__ S1, float* __restrict__ S2) {
    constexpr int NK = K / 32;
    int nt = blockIdx.x, mt = blockIdx.y, b = blockIdx.z;
    int c0 = mt * 128; size_t n0 = (size_t)b * NN + nt * 128;
    __shared__ u16 smem[16384];          // Al0|Al1|Bl0|Bl1 (4K u16 each); epilogue: 128x128 C-tile
    __shared__ float sred[4][64], qred[4][64];
    int t = threadIdx.x, lane = t & 63, w = t >> 6;
    int wr = w >> 1, wc = w & 1;
    f32x4 acc[4][4];
    #pragma unroll
    for (int m = 0; m < 4; ++m)
        #pragma unroll
        for (int n = 0; n < 4; ++n) acc[m][n] = (f32x4){0.f, 0.f, 0.f, 0.f};
    int lr = w * 32 + (lane >> 2);
    int lc = (lane & 3) * 8;

    // prologue: stage K-step 0 into buffer 0
    #pragma unroll
    for (int i = 0; i < 2; ++i) {
        gload16(A + (size_t)(c0 + lr + i * 16) * K + lc, &smem[(w * 32 + i * 16) * 32]);
        gload16(Bm + (n0 + lr + i * 16) * K + lc, &smem[8192 + (w * 32 + i * 16) * 32]);
    }
    __syncthreads();

    for (int ks = 0; ks < NK; ++ks) {
        int cur = ks & 1;
        int an = 4096 * (cur ^ 1), bn2 = 8192 + 4096 * (cur ^ 1);
        int ac = 4096 * cur,       bc  = 8192 + 4096 * cur;
        if (ks + 1 < NK) {
            #pragma unroll
            for (int i = 0; i < 2; ++i) {
                gload16(A + (size_t)(c0 + lr + i * 16) * K + (ks + 1) * 32 + lc, &smem[an + (w * 32 + i * 16) * 32]);
                gload16(Bm + (n0 + lr + i * 16) * K + (ks + 1) * 32 + lc, &smem[bn2 + (w * 32 + i * 16) * 32]);
            }
        }
        bf16x8 af[4], bfr[4];
        #pragma unroll
        for (int m = 0; m < 4; ++m)
            af[m] = *(const bf16x8*)&smem[ac + (wr * 64 + m * 16 + (lane & 15)) * 32 + (lane >> 4) * 8];
        #pragma unroll
        for (int n = 0; n < 4; ++n)
            bfr[n] = *(const bf16x8*)&smem[bc + (wc * 64 + n * 16 + (lane & 15)) * 32 + (lane >> 4) * 8];
        #pragma unroll
        for (int m = 0; m < 4; ++m)
            #pragma unroll
            for (int n = 0; n < 4; ++n)
                acc[m][n] = __builtin_amdgcn_mfma_f32_16x16x32_bf16(af[m], bfr[n], acc[m][n], 0, 0, 0);
        __syncthreads();
    }
    // epilogue: bias + bf16 -> swizzled LDS C-tile + per-channel partial sums (fp32 y, y^2)
    float sacc[4][4], qacc[4][4];
    #pragma unroll
    for (int m = 0; m < 4; ++m) {
        int c = c0 + wr * 64 + m * 16 + (lane >> 4) * 4;
        int clocal = wr * 64 + m * 16 + (lane >> 4) * 4;
        float b0 = bias[c], b1 = bias[c + 1], b2 = bias[c + 2], b3 = bias[c + 3];
        #pragma unroll
        for (int j = 0; j < 4; ++j) { sacc[m][j] = 0.f; qacc[m][j] = 0.f; }
        #pragma unroll
        for (int n = 0; n < 4; ++n) {
            int r = wc * 64 + n * 16 + (lane & 15);      // local row (n-index)
            f32x4 v = acc[m][n];
            float y0 = v[0] + b0, y1 = v[1] + b1, y2 = v[2] + b2, y3 = v[3] + b3;
            u16x4 o;
            o[0] = f2bf(y0); o[1] = f2bf(y1); o[2] = f2bf(y2); o[3] = f2bf(y3);
            *(u16x4*)&smem[r * 128 + (clocal ^ ((r & 7) << 3))] = o;   // swizzled ds_write_b64
            sacc[m][0] += y0; qacc[m][0] += y0 * y0;
            sacc[m][1] += y1; qacc[m][1] += y1 * y1;
            sacc[m][2] += y2; qacc[m][2] += y2 * y2;
            sacc[m][3] += y3; qacc[m][3] += y3 * y3;
        }
    }
    // reduce across the 16 lane-columns (bits 0..3 of lane; bits 4..5 = channel group)
    #pragma unroll
    for (int m = 0; m < 4; ++m)
        #pragma unroll
        for (int j = 0; j < 4; ++j) {
            float s = sacc[m][j], qv = qacc[m][j];
            #pragma unroll
            for (int mask = 1; mask <= 8; mask <<= 1) {
                s  += __shfl_xor(s, mask);
                qv += __shfl_xor(qv, mask);
            }
            sacc[m][j] = s; qacc[m][j] = qv;
        }
    int g = lane >> 4;
    if ((lane & 15) == 0) {
        #pragma unroll
        for (int m = 0; m < 4; ++m)
            #pragma unroll
            for (int j = 0; j < 4; ++j) {
                sred[w][m * 16 + g * 4 + j] = sacc[m][j];
                qred[w][m * 16 + g * 4 + j] = qacc[m][j];
            }
    }
    __syncthreads();
    // coalesced C-tile writeout: 16 lanes cover one full 256B row segment
    #pragma unroll
    for (int p = 0; p < 8; ++p) {
        int r = p * 16 + (t >> 4);
        int chunk = t & 15;
        u16x8 v = *(const u16x8*)&smem[r * 128 + ((chunk * 8) ^ ((r & 7) << 3))];
        *(u16x8*)(Yp + (n0 + r) * CH + c0 + chunk * 8) = v;
    }
    if (t < 128) {
        int half = t >> 6, cl = t & 63;
        float s  = sred[half * 2][cl] + sred[half * 2 + 1][cl];
        float qv = qred[half * 2][cl] + qred[half * 2 + 1][cl];
        atomicAdd(&S1[c0 + half * 64 + cl], s);
        atomicAdd(&S2[c0 + half * 64 + cl], qv);
    }
}

// ---------------- normalize + relu (bf16 -> bf16), BN finalize folded in ----------------
__global__ void k_bnrelu(const u16* __restrict__ Y, const float* __restrict__ S1,
                         const float* __restrict__ S2, const float* __restrict__ gamma,
                         const float* __restrict__ beta, u16* __restrict__ X2) {
    __shared__ float sc[256], sh[256];
    int t = threadIdx.x;
    {
        float inv = 1.f / 65536.f;
        float m = S1[t] * inv;
        float v = S2[t] * inv - m * m;
        float s = gamma[t] * rsqrtf(v + 1e-5f);
        sc[t] = s; sh[t] = beta[t] - m * s;
    }
    __syncthreads();
    size_t i = ((size_t)blockIdx.x * 256 + t) * 8;
    int c = (int)(i & 255);
    u16x8 v = *(const u16x8*)(Y + i);
    u16x8 o;
    #pragma unroll
    for (int k = 0; k < 8; ++k) {
        float f = fmaxf(sc[c + k] * bf2f(v[k]) + sh[c + k], 0.f);
        o[k] = f2bf(f);
    }
    *(u16x8*)(X2 + i) = o;
}

// ---------------- final: normalize + relu + transpose to [B][256][N] f32, finalize folded ----------------
__global__ void k_final(const u16* __restrict__ Y2, const float* __restrict__ S1,
                        const float* __restrict__ S2, const float* __restrict__ gamma,
                        const float* __restrict__ beta, float* __restrict__ out) {
    int b = blockIdx.y, n0 = blockIdx.x * 64;
    __shared__ u16 tile[64 * 256];
    __shared__ float sc[256], sh[256];
    int t = threadIdx.x;
    {
        float inv = 1.f / 65536.f;
        float m = S1[t] * inv;
        float v = S2[t] * inv - m * m;
        float s = gamma[t] * rsqrtf(v + 1e-5f);
        sc[t] = s; sh[t] = beta[t] - m * s;
    }
    #pragma unroll
    for (int p = 0; p < 8; ++p) {
        int r = p * 8 + (t >> 5); int o = t & 31;
        u16x8 v = *(const u16x8*)(Y2 + ((size_t)(b * NN + n0 + r)) * CH + o * 8);
        int osw = o ^ (r & 7);                       // oct-XOR swizzle (keeps 16B alignment)
        *(u16x8*)&tile[r * 256 + osw * 8] = v;
    }
    __syncthreads();
    for (int p = 0; p < 64; ++p) {
        int c = p * 4 + (t >> 6); int n = t & 63;
        int osw = (c >> 3) ^ (n & 7);
        float f = bf2f(tile[n * 256 + osw * 8 + (c & 7)]);
        out[((size_t)(b * CH + c)) * NN + n0 + n] = fmaxf(sc[c] * f + sh[c], 0.f);
    }
}

extern "C" void kernel_launch(void* const* d_in, const int* in_sizes, int n_in,
                              void* d_out, int out_size, void* d_ws, size_t ws_size,
                              hipStream_t stream) {
    const float* f1  = (const float*)d_in[0];
    const float* c1  = (const float*)d_in[1];
    const float* f2  = (const float*)d_in[2];
    const float* c2  = (const float*)d_in[3];
    const float* W1  = (const float*)d_in[4];
    const float* b1  = (const float*)d_in[5];
    const float* g1  = (const float*)d_in[6];
    const float* be1 = (const float*)d_in[7];
    const float* W2  = (const float*)d_in[8];
    const float* b2  = (const float*)d_in[9];
    const float* g2  = (const float*)d_in[10];
    const float* be2 = (const float*)d_in[11];
    float* out = (float*)d_out;
    char* ws = (char*)d_ws;

    u16* Xp    = (u16*)(ws);                    // [65536][384] bf16 = 50,331,648 B
    u16* Y1p   = (u16*)(ws + 50331648);         // [65536][256] bf16 = 33,554,432 B
    u16* X2p   = Xp;                            // reuse (Xp dead after GEMM1)
    u16* Y2p   = Y1p;                           // reuse (Y1p dead after bnrelu)
    u16* W1b   = (u16*)(ws + 83886080);         // 196,608 B
    u16* W2b   = (u16*)(ws + 84082688);         // 131,072 B
    u16* F2t   = (u16*)(ws + 84213760);         // 8,388,608 B
    int*  idxo = (int*)(ws + 92602368);         // 786,432 B
    float* wo  = (float*)(ws + 93388800);       // 786,432 B
    float* stats = (float*)(ws + 94175232);     // 8,192 B
    float* S1a = stats,        *S2a = stats + 256;
    float* S1b = stats + 512,  *S2b = stats + 768;

    (void)hipMemsetAsync(stats, 0, 4096, stream);
    k_convw<<<640, 256, 0, stream>>>(W1, W2, W1b, W2b);
    k_f2t<<<dim3(16, 4, 16), 256, 0, stream>>>(f2, F2t);
    k_knn<<<dim3(64, 16), 512, 0, stream>>>(c1, c2, idxo, wo);
    k_pack<<<dim3(128, 16), 256, 0, stream>>>(f1, F2t, idxo, wo, Xp);
    k_gemm<CIN><<<dim3(32, 2, 16), 256, 0, stream>>>(W1b, Xp, b1, Y1p, S1a, S2a);
    k_bnrelu<<<8192, 256, 0, stream>>>(Y1p, S1a, S2a, g1, be1, X2p);
    k_gemm<CH><<<dim3(32, 2, 16), 256, 0, stream>>>(W2b, X2p, b2, Y2p, S1b, S2b);
    k_final<<<dim3(64, 16), 256, 0, stream>>>(Y2p, S1b, S2b, g2, be2, out);
}